// Round 7
// baseline (379.504 us; speedup 1.0000x reference)
//
#include <hip/hip_runtime.h>
#include <hip/hip_bf16.h>
#include <stdint.h>

#define BATCH 8
#define SEQ   2048
#define EMB   256
#define ADIM  256

typedef __bf16 bf16_t;
typedef __attribute__((ext_vector_type(8))) __bf16 bf16x8;
typedef __attribute__((ext_vector_type(4))) float  f32x4;
typedef uint32_t u32;
typedef __attribute__((ext_vector_type(4))) u32 u32x4;
typedef long long i64;

static __device__ __forceinline__ f32x4 mfma16(bf16x8 a, bf16x8 b, f32x4 c) {
    return __builtin_amdgcn_mfma_f32_16x16x32_bf16(a, b, c, 0, 0, 0);
}

// async global->LDS DMA: lds dest = wave-uniform base + lane*16
static __device__ __forceinline__ void gld16(const void* g, void* l) {
    __builtin_amdgcn_global_load_lds((const __attribute__((address_space(1))) u32*)g,
                                     (__attribute__((address_space(3))) u32*)l, 16, 0, 0);
}

// ---------------- kernel 0: W^T (k,v) cast to bf16 -> d_out scratch ----------------
__global__ __launch_bounds__(256) void wtkv_kernel(const float* __restrict__ Wk,
                                                   const float* __restrict__ Wv,
                                                   bf16_t* __restrict__ wt) {
    int tid = blockIdx.x * 256 + threadIdx.x;   // 0 .. 2*65536-1
    int m = tid >> 16;
    int i = tid & 65535;
    int a = i >> 8, e = i & 255;
    const float* W = (m == 0) ? Wk : Wv;
    wt[m * 65536 + a * 256 + e] = (bf16_t)W[e * 256 + a];
}

// ---------------- kernel 0b: mask -> bit-words ----------------
// bitw word idx = b*131072 + row*64 + w covers mask cols [w*32, w*32+32); bit j set
// iff mask[b][row][w*32+j] != 0. 134 MB int32 -> 4 MB (L2-resident per batch).
__global__ __launch_bounds__(256) void maskbits_kernel(const u32* __restrict__ mask,
                                                       u32* __restrict__ bitw) {
    int idx = blockIdx.x * 256 + threadIdx.x;        // 0 .. 1048575
    const u32* mp = mask + (size_t)idx * 32;         // 128 B contiguous per thread
    u32 wd = 0;
    #pragma unroll
    for (int q = 0; q < 8; ++q) {
        u32x4 v = *(const u32x4*)(mp + q * 4);
        #pragma unroll
        for (int j = 0; j < 4; ++j)
            wd |= (v[j] ? 1u : 0u) << (q * 4 + j);
    }
    bitw[idx] = wd;
}

// ---------------- kernel 1: fused K+V projection, coalesced stores ----------------
// Byte layouts consumed by flash:
//   Ksw: per batch 64 tiles x 16384 B; byte = n*512 + ((cb^(n&7))*16) + j*2
//   Vsw: byte = a*64 + (((k>>3) ^ (a&3) ^ ((a>>2)&3))*16) + (k&7)*2, k = s&31
__global__ __launch_bounds__(128, 1) void proj_kv(const float* __restrict__ x,
                                                  const bf16_t* __restrict__ wt,  // in d_out
                                                  const float* __restrict__ bk,
                                                  const float* __restrict__ bv,
                                                  char* __restrict__ Ksw,
                                                  char* __restrict__ Vsw) {
    __shared__ __align__(16) char stg[2][10240];   // per-wave repack buffer
    const int tid  = threadIdx.x;
    const int wid  = tid >> 6;
    const int lane = tid & 63;
    const int lq   = lane >> 4;
    const int ln   = lane & 15;
    const int blk  = blockIdx.x;                   // 0..511: one 32-row tile
    const int b    = blk >> 6;                     // batch
    const int tile = blk & 63;                     // tile within batch
    const int mbase = blk * 32 + wid * 16;         // this wave's 16 global rows
    char* S = stg[wid];

    bf16x8 xf[8];
    const float* xp = x + (size_t)(mbase + ln) * EMB;
    #pragma unroll
    for (int c = 0; c < 8; ++c) {
        f32x4 a0 = *(const f32x4*)(xp + c * 32 + lq * 8);
        f32x4 a1 = *(const f32x4*)(xp + c * 32 + lq * 8 + 4);
        bf16x8 v;
        v[0] = (bf16_t)a0[0]; v[1] = (bf16_t)a0[1]; v[2] = (bf16_t)a0[2]; v[3] = (bf16_t)a0[3];
        v[4] = (bf16_t)a1[0]; v[5] = (bf16_t)a1[1]; v[6] = (bf16_t)a1[2]; v[7] = (bf16_t)a1[3];
        xf[c] = v;
    }

    f32x4 acc[16];

    // ======== K projection ========
    #pragma unroll
    for (int t = 0; t < 16; ++t) acc[t] = (f32x4){0.f, 0.f, 0.f, 0.f};
    {
        const bf16_t* w = wt;                      // K panel wt[0][a][e]
        #pragma unroll
        for (int c = 0; c < 8; ++c)
            #pragma unroll
            for (int t = 0; t < 16; ++t) {
                bf16x8 wf = *(const bf16x8*)(w + (size_t)(t * 16 + ln) * 256 + c * 32 + lq * 8);
                acc[t] = mfma16(xf[c], wf, acc[t]);
            }
    }
    #pragma unroll
    for (int t = 0; t < 16; ++t) {
        float bb = bk[t * 16 + ln];
        #pragma unroll
        for (int r = 0; r < 4; ++r)
            *(bf16_t*)(S + (lq * 4 + r) * 512 + (t * 16 + ln) * 2) = (bf16_t)(acc[t][r] + bb);
    }
    asm volatile("s_waitcnt lgkmcnt(0)" ::: "memory");
    {
        char* Kg = Ksw + (size_t)b * 1048576 + (size_t)tile * 16384 + wid * 8192;
        const int rh = lane >> 5;
        const int p  = lane & 31;
        #pragma unroll
        for (int i = 0; i < 8; ++i) {
            int row = i * 2 + rh;
            int n   = wid * 16 + row;
            int cb  = p ^ (n & 7);
            f32x4 ch = *(const f32x4*)(S + row * 512 + cb * 16);
            *(f32x4*)(Kg + row * 512 + p * 16) = ch;
        }
    }

    // ======== V projection ========
    #pragma unroll
    for (int t = 0; t < 16; ++t) acc[t] = (f32x4){0.f, 0.f, 0.f, 0.f};
    {
        const bf16_t* w = wt + 65536;              // V panel wt[1][a][e]
        #pragma unroll
        for (int c = 0; c < 8; ++c)
            #pragma unroll
            for (int t = 0; t < 16; ++t) {
                bf16x8 wf = *(const bf16x8*)(w + (size_t)(t * 16 + ln) * 256 + c * 32 + lq * 8);
                acc[t] = mfma16(xf[c], wf, acc[t]);
            }
    }
    #pragma unroll
    for (int t = 0; t < 16; ++t) {
        float bb = bv[t * 16 + ln];
        #pragma unroll
        for (int r = 0; r < 4; ++r)
            *(bf16_t*)(S + (t * 16 + ln) * 40 + (lq * 4 + r) * 2) = (bf16_t)(acc[t][r] + bb);
    }
    asm volatile("s_waitcnt lgkmcnt(0)" ::: "memory");
    {
        char* Vg = Vsw + (size_t)b * 1048576 + (size_t)tile * 16384;
        const int half = lane & 1;
        const int kq   = wid * 2 + half;
        #pragma unroll
        for (int i = 0; i < 8; ++i) {
            int a   = i * 32 + (lane >> 1);
            int pos = kq ^ (a & 3) ^ ((a >> 2) & 3);
            f32x4 ch = *(const f32x4*)(S + a * 40 + half * 16);
            *(f32x4*)(Vg + a * 64 + pos * 16) = ch;
        }
    }
}

// ---------------- kernel 2: fused masked attention, KV-split, 8-wave blocks ----------------
// R6 change: 512-thread blocks (8 waves) doing the SAME 64-q-row x 32-kv-tile work,
// each wave handling HALF the old per-wave load (16 q rows, one s accumulator, o[8]).
// 2 blocks/CU co-resident (LDS 76288*2 = 152576 <= 163840) -> 16 waves/CU = 4/SIMD,
// double the wave-level parallelism to hide dependent-MFMA latency, LDS latency and
// the 2 barriers/iter (counters: all pipes <=16% busy at 2 waves/SIMD = latency-bound).
// __launch_bounds__(512,4) caps VGPR at 128 (required for 4 waves/SIMD; est. need ~115).
// Wave roles: qw = wid>>1 (16 q rows), kw = wid&1 (16 kv cols). DMA: wid<4 copy K
// quarters, wid>=4 copy V quarters -> identical LDS image to the proven R0 layout.
// Counted top barrier: vmcnt(4) retires this tile's 4 DMA, keeps the 4 young mask
// loads in flight. Bitmask ring + lp parking retained from R4/R6.
__global__ __launch_bounds__(512, 4) void flash_kernel(const float* __restrict__ x,
                                                       const float* __restrict__ WqM,
                                                       const float* __restrict__ bq,
                                                       const char* __restrict__ Ksw,
                                                       const char* __restrict__ Vsw,
                                                       const int* __restrict__ mask,
                                                       const u32* __restrict__ bitw,
                                                       float* __restrict__ lp,
                                                       i64 bs, i64 rs, i64 ks,
                                                       float* __restrict__ out) {
    // LDS: [K0 16K][V0 16K][K1 16K][V1 16K] @0 ; Pq 4x1280 @65536 (aliases prologue
    // Pt 8x1280 @65536..75776 — last Pt read precedes kt=0 top barrier) ; Ls @75776.
    __shared__ __align__(16) char smem[76288];
    const int tid  = threadIdx.x;
    const int wid  = tid >> 6;    // 0..7
    const int lane = tid & 63;
    const int lq   = lane >> 4;
    const int ln   = lane & 15;
    const int qw   = wid >> 1;    // q quarter (16 rows)
    const int kw   = wid & 1;     // kv col half within tile (16 cols)
    const int batch = blockIdx.x & 7;
    const int kvh   = (blockIdx.x >> 3) & 1;     // kv half of the sequence
    const int qbase = (blockIdx.x >> 4) * 64;

    const char* Kb = Ksw + (size_t)batch * 1048576 + (size_t)(kvh * 32) * 16384;
    const char* Vb = Vsw + (size_t)batch * 1048576 + (size_t)(kvh * 32) * 16384;
    char*  Pq_ = smem + 65536 + qw * 1280;       // shared by kw pair: 16 rows x 80 B
    char*  Pt  = smem + 65536 + wid * 1280;      // wave-private (prologue only)
    float* Ls  = (float*)(smem + 75776);

    // DMA role: waves 0-3 copy K quarters, waves 4-7 copy V quarters (4 KB each)
    const int dhalf = wid >> 2, dqr = wid & 3;
    const char* gsrc0 = (dhalf ? Vb : Kb) + dqr * 4096 + lane * 16;
    const int   ldst0 = dhalf * 16384 + dqr * 4096;

    // raw mask base for this wave's 16 rows and its kv-col strip
    const int* mroot = mask + (size_t)batch * SEQ * SEQ +
                       (size_t)(qbase + qw * 16) * SEQ + kvh * 1024 + kw * 16 + ln;
    // bit-word base: word index = row*64 + kvh*32 + kt ; bit = kw*16 + ln
    const u32* broot = bitw ? bitw + (size_t)batch * 131072 +
                              (size_t)(qbase + qw * 16) * 64 + kvh * 32
                            : nullptr;
    const int bitpos = kw * 16 + ln;

    // ---- issue DMA for tile 0 (latency covered by Q prologue) ----
    {
        char* dl = smem + ldst0;
        #pragma unroll
        for (int i = 0; i < 4; ++i) gld16(gsrc0 + i * 1024, dl + i * 1024);
    }
    // pin the prefills AFTER the DMA in issue order (keeps vmcnt counting sound)
    asm volatile("" ::: "memory");
    // mask ring prefill for kt = 0,1 (completes during prologue)
    int mv[2][4];
    if (broot) {
        #pragma unroll
        for (int w = 0; w < 2; ++w)
            #pragma unroll
            for (int r = 0; r < 4; ++r)
                mv[w][r] = (int)((broot[(lq * 4 + r) * 64 + w] >> bitpos) & 1u);
    } else {
        #pragma unroll
        for (int w = 0; w < 2; ++w)
            #pragma unroll
            for (int r = 0; r < 4; ++r)
                mv[w][r] = mroot[(size_t)(lq * 4 + r) * SEQ + w * 32];
    }

    // ---- Q prologue: this wave's 16 rows -> A-fragments qf[c] ----
    bf16x8 qf[8];
    {
        bf16x8 xf[8];
        {
            const float* xp = x + (size_t)(batch * SEQ + qbase + qw * 16 + ln) * EMB;
            #pragma unroll
            for (int c = 0; c < 8; ++c) {
                f32x4 a = *(const f32x4*)(xp + c * 32 + lq * 8);
                f32x4 b = *(const f32x4*)(xp + c * 32 + lq * 8 + 4);
                bf16x8 v;
                v[0] = (bf16_t)a[0]; v[1] = (bf16_t)a[1]; v[2] = (bf16_t)a[2]; v[3] = (bf16_t)a[3];
                v[4] = (bf16_t)b[0]; v[5] = (bf16_t)b[1]; v[6] = (bf16_t)b[2]; v[7] = (bf16_t)b[3];
                xf[c] = v;
            }
        }
        f32x4 qacc[16];
        #pragma unroll
        for (int t = 0; t < 16; ++t) qacc[t] = (f32x4){0.f, 0.f, 0.f, 0.f};

        char* Wsp = smem + 32768;                // buf1 as panel scratch (tile1 DMA is later)
        const int grp = tid >> 8;                // 0,1: which pair of e-slices this thread stages
        const int aa  = tid & 255;               // a-row staged by this thread
        const int e   = ln & 7;
        #pragma unroll 1
        for (int cp = 0; cp < 8; ++cp) {
            __syncthreads();
            const float* wqp = WqM + (size_t)(cp * 32) * 256 + aa;
            #pragma unroll
            for (int i = 0; i < 2; ++i) {
                int ip = grp * 2 + i;
                bf16x8 pk;
                #pragma unroll
                for (int j = 0; j < 8; ++j)
                    pk[j] = (bf16_t)wqp[(size_t)(ip * 8 + j) * 256];
                *(bf16x8*)(Wsp + aa * 128 + ((ip ^ (aa & 7)) * 16)) = pk;
            }
            __syncthreads();
            #pragma unroll
            for (int t = 0; t < 16; ++t) {
                bf16x8 wf = *(const bf16x8*)(Wsp + (t * 16 + ln) * 128 + ((lq ^ e) * 16));
                qacc[t] = mfma16(xf[cp], wf, qacc[t]);
            }
        }
        // C-layout -> A-layout via wave-private Pt; fold bias and 1/sqrt(A)=1/16
        #pragma unroll
        for (int c = 0; c < 8; ++c) {
            #pragma unroll
            for (int half2 = 0; half2 < 2; ++half2) {
                int t = 2 * c + half2;
                float bb = bq[t * 16 + ln];
                #pragma unroll
                for (int r = 0; r < 4; ++r) {
                    float v = (qacc[t][r] + bb) * 0.0625f;
                    ((bf16_t*)(Pt + (lq * 4 + r) * 80))[half2 * 16 + ln] = (bf16_t)v;
                }
            }
            qf[c] = *(const bf16x8*)(Pt + ln * 80 + lq * 16);
        }
    }

    // ---- main loop: 32 iterations over this block's kv half ----
    f32x4 o[8];
    #pragma unroll
    for (int t = 0; t < 8; ++t) o[t] = (f32x4){0.f, 0.f, 0.f, 0.f};
    float lsum[4] = {0.f, 0.f, 0.f, 0.f};

    const int kswz = ln & 7;
    const int vswz = (lq ^ (ln & 3) ^ ((ln >> 2) & 3)) * 16;
    const int n0   = kw * 16 + ln;

    for (int kt = 0; kt < 32; ++kt) {
        // counted TOP barrier: retire this tile's 4 DMA (oldest), keep the 4 young
        // mask loads in flight; drain own LDS ops (Pq WAR safety).
        asm volatile("s_waitcnt vmcnt(4) lgkmcnt(0)\n\ts_barrier" ::: "memory");
        if (kt + 1 < 32) {                        // prefetch tile kt+1 (this wave's 4 KB)
            const char* gs = gsrc0 + (size_t)(kt + 1) * 16384;
            char* dl = smem + ((kt + 1) & 1) * 32768 + ldst0;
            #pragma unroll
            for (int i = 0; i < 4; ++i) gld16(gs + i * 1024, dl + i * 1024);
        }
        const char* Ksb = smem + (kt & 1) * 32768;
        const char* Vsb = Ksb + 16384;

        // S = Q K^T (this wave's 16 q rows x 16 kv cols)
        f32x4 s0 = (f32x4){0.f, 0.f, 0.f, 0.f};
        const char* krow = Ksb + n0 * 512;
        #pragma unroll
        for (int c = 0; c < 8; ++c) {
            bf16x8 kf = *(const bf16x8*)(krow + (((c * 4 + lq) ^ kswz) * 16));
            s0 = mfma16(qf[c], kf, s0);
        }

        // p = mask ? exp(s) : 0 (ring slot loaded 1.5 iters ago -> wait-free)
        const int* mc = mv[kt & 1];
        #pragma unroll
        for (int r = 0; r < 4; ++r) {
            float p0 = mc[r] ? __expf(s0[r]) : 0.f;
            lsum[r] += p0;
            ((bf16_t*)(Pq_ + (lq * 4 + r) * 80))[kw * 16 + ln] = (bf16_t)p0;
        }

        // P-exchange: drain LDS only — prefetch DMA stays in flight
        asm volatile("s_waitcnt lgkmcnt(0)\n\ts_barrier" ::: "memory");

        // refill ring slot for kt+2 — BETWEEN the asm barriers, so these 4 loads
        // are provably the only post-DMA vmem ops (top barrier's vmcnt(4)).
        {
            const int ktn = (kt + 2 < 32) ? kt + 2 : 31;
            int* md = mv[kt & 1];
            if (broot) {
                #pragma unroll
                for (int r = 0; r < 4; ++r)
                    md[r] = (int)((broot[(lq * 4 + r) * 64 + ktn] >> bitpos) & 1u);
            } else {
                #pragma unroll
                for (int r = 0; r < 4; ++r)
                    md[r] = mroot[(size_t)(lq * 4 + r) * SEQ + ktn * 32];
            }
        }

        bf16x8 pa0 = *(const bf16x8*)(Pq_ + ln * 80 + lq * 16);

        // O += P V (this wave's 128 a-cols for its 16 q rows)
        const char* vbase = Vsb + (kw * 128 + ln) * 64 + vswz;
        #pragma unroll
        for (int t = 0; t < 8; ++t) {
            bf16x8 vf = *(const bf16x8*)(vbase + t * 1024);
            o[t] = mfma16(pa0, vf, o[t]);
        }
    }

    __syncthreads();
    // partial row-sum: reduce over the 16 ln lanes, publish, combine kw halves
    #pragma unroll
    for (int r = 0; r < 4; ++r) {
        float v = lsum[r];
        v += __shfl_xor(v, 1);
        v += __shfl_xor(v, 2);
        v += __shfl_xor(v, 4);
        v += __shfl_xor(v, 8);
        if (ln == 0) Ls[(qw * 2 + kw) * 16 + lq * 4 + r] = v;
        lsum[r] = v;
    }
    __syncthreads();

    // park this block's per-row partial lsum (lp: d_ws in ws-mode, mask slot fallback)
    if (kw == 0 && ln == 0) {
        #pragma unroll
        for (int r = 0; r < 4; ++r) {
            int row = lq * 4 + r;
            float tot = lsum[r] + Ls[(qw * 2 + 1) * 16 + row];
            lp[bs * batch + rs * (qbase + qw * 16 + row) + ks * kvh] = tot;
        }
    }

    // accumulate unnormalized partial O into zeroed d_out
    #pragma unroll
    for (int r = 0; r < 4; ++r) {
        float* orow = out + (size_t)(batch * SEQ + qbase + qw * 16 + lq * 4 + r) * ADIM
                      + kw * 128 + ln;
        #pragma unroll
        for (int t = 0; t < 8; ++t)
            atomicAdd(orow + t * 16, o[t][r]);
    }
}

// ---------------- kernel 3: merge/normalize ----------------
// out[row][:] /= (l0[row] + l1[row]) with partial lsums read via (lp, strides).
__global__ __launch_bounds__(256) void merge_kernel(const float* __restrict__ lp,
                                                    i64 bs, i64 rs, i64 ks,
                                                    float* __restrict__ out) {
    int idx  = blockIdx.x * 256 + threadIdx.x;   // x4 elements
    int base = idx * 4;                          // 0 .. 16,777,212
    int row  = base >> 8;                        // global row 0..16383
    int b = row >> 11, r = row & 2047;
    float l0 = lp[bs * b + rs * r];
    float l1 = lp[bs * b + rs * r + ks];
    float inv = 1.0f / (l0 + l1);
    f32x4 v = *(const f32x4*)(out + base);
    v[0] *= inv; v[1] *= inv; v[2] *= inv; v[3] *= inv;
    *(f32x4*)(out + base) = v;
}

// ================= launch =================
extern "C" void kernel_launch(void* const* d_in, const int* in_sizes, int n_in,
                              void* d_out, int out_size, void* d_ws, size_t ws_size,
                              hipStream_t stream) {
    const float* x    = (const float*)d_in[0];
    int*         mask = (int*)d_in[1];
    const float* Wq   = (const float*)d_in[2];
    const float* bq   = (const float*)d_in[3];
    const float* Wk   = (const float*)d_in[4];
    const float* bk   = (const float*)d_in[5];
    const float* Wv   = (const float*)d_in[6];
    const float* bv   = (const float*)d_in[7];
    float* out = (float*)d_out;

    // ws: K_sw [0..8MB) | V_sw [8..16MB) | bitw [16..20MB) | lsum park [20MB..+128KB)
    char* Ksw = (char*)d_ws;
    char* Vsw = Ksw + (size_t)8 * 1024 * 1024;
    bf16_t* wt = (bf16_t*)d_out;                 // W^T bf16 scratch, consumed by proj

    const size_t MB = 1024 * 1024;
    const size_t lsum_bytes = (size_t)2 * BATCH * SEQ * sizeof(float);   // 128 KB
    u32*   bitw = nullptr;
    float* lp; i64 bs, rs, ks;
    if (ws_size >= 20 * MB + lsum_bytes) {       // bit-mask tier (engaged in R6)
        bitw = (u32*)(Ksw + 16 * MB);
        lp = (float*)(Ksw + 20 * MB);
        bs = (i64)2 * SEQ;  rs = 2;  ks = 1;
    } else if (ws_size >= 16 * MB + lsum_bytes) { // ws-lsum tier
        lp = (float*)(Ksw + 16 * MB);
        bs = (i64)2 * SEQ;  rs = 2;  ks = 1;
    } else {                                      // legacy in-mask parking
        lp = (float*)mask;
        bs = (i64)SEQ * SEQ;  rs = SEQ;  ks = 1024;
    }

    wtkv_kernel<<<512, 256, 0, stream>>>(Wk, Wv, wt);
    if (bitw) maskbits_kernel<<<4096, 256, 0, stream>>>((const u32*)mask, bitw);
    proj_kv<<<512, 128, 0, stream>>>(x, wt, bk, bv, Ksw, Vsw);
    // zero the f32 accumulator AFTER proj consumed wt (stream-ordered; graph-legal)
    hipMemsetAsync(d_out, 0, (size_t)out_size * sizeof(float), stream);
    flash_kernel<<<512, 512, 0, stream>>>(x, Wq, bq, Ksw, Vsw, mask, bitw,
                                          lp, bs, rs, ks, out);
    merge_kernel<<<4096, 256, 0, stream>>>(lp, bs, rs, ks, out);
}

// Round 8
// 359.828 us; speedup vs baseline: 1.0547x; 1.0547x over previous
//
#include <hip/hip_runtime.h>
#include <hip/hip_bf16.h>
#include <stdint.h>

#define BATCH 8
#define SEQ   2048
#define EMB   256
#define ADIM  256

typedef __bf16 bf16_t;
typedef __attribute__((ext_vector_type(8))) __bf16 bf16x8;
typedef __attribute__((ext_vector_type(4))) float  f32x4;
typedef uint32_t u32;
typedef __attribute__((ext_vector_type(4))) u32 u32x4;
typedef long long i64;

static __device__ __forceinline__ f32x4 mfma16(bf16x8 a, bf16x8 b, f32x4 c) {
    return __builtin_amdgcn_mfma_f32_16x16x32_bf16(a, b, c, 0, 0, 0);
}

// async global->LDS DMA: lds dest = wave-uniform base + lane*16
static __device__ __forceinline__ void gld16(const void* g, void* l) {
    __builtin_amdgcn_global_load_lds((const __attribute__((address_space(1))) u32*)g,
                                     (__attribute__((address_space(3))) u32*)l, 16, 0, 0);
}

// pack two f32 -> one u32 of two bf16 (RNE, same rounding as scalar casts)
static __device__ __forceinline__ u32 pk2(float lo, float hi) {
    u32 a = (u32)__builtin_bit_cast(unsigned short, (bf16_t)lo);
    u32 b = (u32)__builtin_bit_cast(unsigned short, (bf16_t)hi);
    return a | (b << 16);
}

// ---------------- kernel 0: W^T (k,v,q) cast to bf16 -> d_out scratch ----------------
// wt[m][a][e] = (bf16) W_m[e][a], m = 0:K 1:V 2:Q. d_out is dead for flash output
// until the memset; only proj (stream-ordered before it) reads wt.
__global__ __launch_bounds__(256) void wtkv_kernel(const float* __restrict__ Wk,
                                                   const float* __restrict__ Wv,
                                                   const float* __restrict__ Wq,
                                                   bf16_t* __restrict__ wt) {
    int tid = blockIdx.x * 256 + threadIdx.x;   // 0 .. 3*65536-1
    int m = tid >> 16;
    int i = tid & 65535;
    int a = i >> 8, e = i & 255;
    const float* W = (m == 0) ? Wk : (m == 1) ? Wv : Wq;
    wt[m * 65536 + a * 256 + e] = (bf16_t)W[e * 256 + a];
}

// ---------------- kernel 0b: mask -> bit-words ----------------
// bitw word idx = b*131072 + row*64 + w covers mask cols [w*32, w*32+32); bit j set
// iff mask[b][row][w*32+j] != 0. 134 MB int32 -> 4 MB (L2-resident per batch).
__global__ __launch_bounds__(256) void maskbits_kernel(const u32* __restrict__ mask,
                                                       u32* __restrict__ bitw) {
    int idx = blockIdx.x * 256 + threadIdx.x;        // 0 .. 1048575
    const u32* mp = mask + (size_t)idx * 32;         // 128 B contiguous per thread
    u32 wd = 0;
    #pragma unroll
    for (int q = 0; q < 8; ++q) {
        u32x4 v = *(const u32x4*)(mp + q * 4);
        #pragma unroll
        for (int j = 0; j < 4; ++j)
            wd |= (v[j] ? 1u : 0u) << (q * 4 + j);
    }
    bitw[idx] = wd;
}

// ---------------- kernel 1: fused K+V(+Q) projection, coalesced stores ----------------
// Byte layouts consumed by flash (K-format also used for Qsw):
//   Ksw: per batch 64 tiles x 16384 B; byte = n*512 + ((cb^(n&7))*16) + j*2
//   Vsw: byte = a*64 + (((k>>3) ^ (a&3) ^ ((a>>2)&3))*16) + (k&7)*2, k = s&31
// Q panel folds bias and 1/sqrt(A)=1/16 (identical math/order to the old flash
// prologue: (acc+b)*0.0625 cast to bf16) and stores in K-format to Qsw.
__global__ __launch_bounds__(128, 1) void proj_qkv(const float* __restrict__ x,
                                                   const bf16_t* __restrict__ wt,  // in d_out
                                                   const float* __restrict__ bk,
                                                   const float* __restrict__ bv,
                                                   const float* __restrict__ bq,
                                                   char* __restrict__ Ksw,
                                                   char* __restrict__ Vsw,
                                                   char* __restrict__ Qsw) {
    __shared__ __align__(16) char stg[2][10240];   // per-wave repack buffer
    const int tid  = threadIdx.x;
    const int wid  = tid >> 6;
    const int lane = tid & 63;
    const int lq   = lane >> 4;
    const int ln   = lane & 15;
    const int blk  = blockIdx.x;                   // 0..511: one 32-row tile
    const int b    = blk >> 6;                     // batch
    const int tile = blk & 63;                     // tile within batch
    const int mbase = blk * 32 + wid * 16;         // this wave's 16 global rows
    char* S = stg[wid];

    bf16x8 xf[8];
    const float* xp = x + (size_t)(mbase + ln) * EMB;
    #pragma unroll
    for (int c = 0; c < 8; ++c) {
        f32x4 a0 = *(const f32x4*)(xp + c * 32 + lq * 8);
        f32x4 a1 = *(const f32x4*)(xp + c * 32 + lq * 8 + 4);
        bf16x8 v;
        v[0] = (bf16_t)a0[0]; v[1] = (bf16_t)a0[1]; v[2] = (bf16_t)a0[2]; v[3] = (bf16_t)a0[3];
        v[4] = (bf16_t)a1[0]; v[5] = (bf16_t)a1[1]; v[6] = (bf16_t)a1[2]; v[7] = (bf16_t)a1[3];
        xf[c] = v;
    }

    f32x4 acc[16];

    // ======== K projection ========
    #pragma unroll
    for (int t = 0; t < 16; ++t) acc[t] = (f32x4){0.f, 0.f, 0.f, 0.f};
    {
        const bf16_t* w = wt;                      // K panel wt[0][a][e]
        #pragma unroll
        for (int c = 0; c < 8; ++c)
            #pragma unroll
            for (int t = 0; t < 16; ++t) {
                bf16x8 wf = *(const bf16x8*)(w + (size_t)(t * 16 + ln) * 256 + c * 32 + lq * 8);
                acc[t] = mfma16(xf[c], wf, acc[t]);
            }
    }
    #pragma unroll
    for (int t = 0; t < 16; ++t) {
        float bb = bk[t * 16 + ln];
        #pragma unroll
        for (int r = 0; r < 4; ++r)
            *(bf16_t*)(S + (lq * 4 + r) * 512 + (t * 16 + ln) * 2) = (bf16_t)(acc[t][r] + bb);
    }
    asm volatile("s_waitcnt lgkmcnt(0)" ::: "memory");
    {
        char* Kg = Ksw + (size_t)b * 1048576 + (size_t)tile * 16384 + wid * 8192;
        const int rh = lane >> 5;
        const int p  = lane & 31;
        #pragma unroll
        for (int i = 0; i < 8; ++i) {
            int row = i * 2 + rh;
            int n   = wid * 16 + row;
            int cb  = p ^ (n & 7);
            f32x4 ch = *(const f32x4*)(S + row * 512 + cb * 16);
            *(f32x4*)(Kg + row * 512 + p * 16) = ch;
        }
    }

    // ======== Q projection (K-format store; only when Qsw tier engaged) ========
    if (Qsw) {
        #pragma unroll
        for (int t = 0; t < 16; ++t) acc[t] = (f32x4){0.f, 0.f, 0.f, 0.f};
        {
            const bf16_t* w = wt + 131072;         // Q panel wt[2][a][e]
            #pragma unroll
            for (int c = 0; c < 8; ++c)
                #pragma unroll
                for (int t = 0; t < 16; ++t) {
                    bf16x8 wf = *(const bf16x8*)(w + (size_t)(t * 16 + ln) * 256 + c * 32 + lq * 8);
                    acc[t] = mfma16(xf[c], wf, acc[t]);
                }
        }
        #pragma unroll
        for (int t = 0; t < 16; ++t) {
            float bb = bq[t * 16 + ln];
            #pragma unroll
            for (int r = 0; r < 4; ++r)
                *(bf16_t*)(S + (lq * 4 + r) * 512 + (t * 16 + ln) * 2) =
                    (bf16_t)((acc[t][r] + bb) * 0.0625f);
        }
        asm volatile("s_waitcnt lgkmcnt(0)" ::: "memory");
        {
            char* Qg = Qsw + (size_t)b * 1048576 + (size_t)tile * 16384 + wid * 8192;
            const int rh = lane >> 5;
            const int p  = lane & 31;
            #pragma unroll
            for (int i = 0; i < 8; ++i) {
                int row = i * 2 + rh;
                int n   = wid * 16 + row;
                int cb  = p ^ (n & 7);
                f32x4 ch = *(const f32x4*)(S + row * 512 + cb * 16);
                *(f32x4*)(Qg + row * 512 + p * 16) = ch;
            }
        }
    }

    // ======== V projection ========
    #pragma unroll
    for (int t = 0; t < 16; ++t) acc[t] = (f32x4){0.f, 0.f, 0.f, 0.f};
    {
        const bf16_t* w = wt + 65536;              // V panel wt[1][a][e]
        #pragma unroll
        for (int c = 0; c < 8; ++c)
            #pragma unroll
            for (int t = 0; t < 16; ++t) {
                bf16x8 wf = *(const bf16x8*)(w + (size_t)(t * 16 + ln) * 256 + c * 32 + lq * 8);
                acc[t] = mfma16(xf[c], wf, acc[t]);
            }
    }
    #pragma unroll
    for (int t = 0; t < 16; ++t) {
        float bb = bv[t * 16 + ln];
        #pragma unroll
        for (int r = 0; r < 4; ++r)
            *(bf16_t*)(S + (t * 16 + ln) * 40 + (lq * 4 + r) * 2) = (bf16_t)(acc[t][r] + bb);
    }
    asm volatile("s_waitcnt lgkmcnt(0)" ::: "memory");
    {
        char* Vg = Vsw + (size_t)b * 1048576 + (size_t)tile * 16384;
        const int half = lane & 1;
        const int kq   = wid * 2 + half;
        #pragma unroll
        for (int i = 0; i < 8; ++i) {
            int a   = i * 32 + (lane >> 1);
            int pos = kq ^ (a & 3) ^ ((a >> 2) & 3);
            f32x4 ch = *(const f32x4*)(S + a * 40 + half * 16);
            *(f32x4*)(Vg + a * 64 + pos * 16) = ch;
        }
    }
}

// ---------------- kernel 2 (PRIMARY): barrier-light flash, swapped QK ----------------
// R7 structure: 4 waves x 256 threads; wave owns 16 q rows x full 32-kv tile x all
// 256 a-cols. Q read from pre-swizzled Qsw (8 b128 loads — the 16-barrier Wq
// prologue is gone). Swapped QK (S^T = mfma(kf, qf)) makes each q-row's P
// lane-local: the PV A-fragment is built in-register via 4 packs + 8 ds_bpermute
// + 4 selects — NO mid barrier, NO Pq LDS, no ds_write anywhere in the loop.
// Mask: one bit-word per lane per tile (q row ln's 32 kv bits).
// Sole sync: counted top barrier s_waitcnt vmcnt(1) lgkmcnt(0); s_barrier —
// retires this tile's 8 DMA, keeps the 1 young mask word in flight.
// LDS 64 KB (KV dbuf only) -> 2 blocks/CU. O/lsum merge across kvh unchanged
// (atomicAdd + lp parking + merge_kernel).
__global__ __launch_bounds__(256, 2) void flash_kernel(const char* __restrict__ Qsw,
                                                       const char* __restrict__ Ksw,
                                                       const char* __restrict__ Vsw,
                                                       const u32* __restrict__ bitw,
                                                       float* __restrict__ lp,
                                                       i64 bs, i64 rs, i64 ks,
                                                       float* __restrict__ out) {
    // LDS: buf0 [K 16K][V 16K] @0 ; buf1 @32768.
    __shared__ __align__(16) char smem[65536];
    const int tid  = threadIdx.x;
    const int wid  = tid >> 6;    // 0..3: 16-q-row group
    const int lane = tid & 63;
    const int lq   = lane >> 4;
    const int ln   = lane & 15;
    const int batch = blockIdx.x & 7;
    const int kvh   = (blockIdx.x >> 3) & 1;     // kv half of the sequence
    const int qbase = (blockIdx.x >> 4) * 64;

    const char* Kb = Ksw + (size_t)batch * 1048576 + (size_t)(kvh * 32) * 16384;
    const char* Vb = Vsw + (size_t)batch * 1048576 + (size_t)(kvh * 32) * 16384;

    // DMA role: wid 0,1 stage K halves; wid 2,3 stage V halves (8 KB each)
    const char* gsrc0 = ((wid & 2) ? Vb : Kb) + (wid & 1) * 8192 + lane * 16;
    const int   ldst0 = (wid & 2) * 8192 + (wid & 1) * 8192;   // (wid&2)*8192 = 16384 for V

    // ---- issue DMA for tile 0 (oldest vmem ops by construction) ----
    #pragma unroll
    for (int i = 0; i < 8; ++i) gld16(gsrc0 + i * 1024, smem + ldst0 + i * 1024);
    asm volatile("" ::: "memory");

    // mask ring: one word = q row (ln)'s 32 kv bits for tile kt
    const u32* broot = bitw + (size_t)batch * 131072 +
                       (size_t)(qbase + wid * 16 + ln) * 64 + kvh * 32;
    u32 mwv[2];
    mwv[0] = broot[0];
    mwv[1] = broot[1];

    // ---- Q fragments straight from Qsw (K-format; swizzle = row&7) ----
    bf16x8 qf[8];
    {
        const int qr = qbase + wid * 16 + ln;
        const char* qp = Qsw + (size_t)batch * 1048576 +
                         (size_t)(qr >> 5) * 16384 + (size_t)(qr & 31) * 512;
        const int qswz = ln & 7;                  // (qr&31)&7 == ln&7
        #pragma unroll
        for (int c = 0; c < 8; ++c)
            qf[c] = *(const bf16x8*)(qp + (((c * 4 + lq) ^ qswz) * 16));
    }

    f32x4 o[16];
    #pragma unroll
    for (int t = 0; t < 16; ++t) o[t] = (f32x4){0.f, 0.f, 0.f, 0.f};
    float lsum = 0.f;

    const int kswz = ln & 7;
    const int vswz = (lq ^ (ln & 3) ^ ((ln >> 2) & 3)) * 16;
    const int lq4  = lq * 4;
    const int iA   = (((lq & 1) * 2) * 16 + ln) * 4;   // bpermute byte index, lane A
    const int iB   = iA + 64;                          // lane A + 16
    const bool lqhi = (lq & 2) != 0;                   // kv half selector

    for (int kt = 0; kt < 32; ++kt) {
        // counted TOP barrier: retire this tile's 8 DMA (oldest), keep the young
        // mask word in flight; drain own LDS ops (buffer WAR safety for all waves).
        asm volatile("s_waitcnt vmcnt(1) lgkmcnt(0)\n\ts_barrier" ::: "memory");
        if (kt + 1 < 32) {                        // prefetch tile kt+1 (8 KB per wave)
            const char* gs = gsrc0 + (size_t)(kt + 1) * 16384;
            char* dl = smem + ((kt + 1) & 1) * 32768 + ldst0;
            #pragma unroll
            for (int i = 0; i < 8; ++i) gld16(gs + i * 1024, dl + i * 1024);
        }
        const char* Ksb = smem + (kt & 1) * 32768;
        const char* Vsb = Ksb + 16384;

        // S^T = K Q^T : lane (lq,ln) gets S^T[kv = h*16+lq*4+r][q row = ln]
        f32x4 sa = (f32x4){0.f, 0.f, 0.f, 0.f};
        f32x4 sb = (f32x4){0.f, 0.f, 0.f, 0.f};
        const char* krowa = Ksb + ln * 512;
        const char* krowb = Ksb + (16 + ln) * 512;
        #pragma unroll
        for (int c = 0; c < 8; ++c) {
            const int off = ((c * 4 + lq) ^ kswz) * 16;
            bf16x8 ka = *(const bf16x8*)(krowa + off);
            bf16x8 kb = *(const bf16x8*)(krowb + off);
            sa = mfma16(ka, qf[c], sa);
            sb = mfma16(kb, qf[c], sb);
        }

        // p = mask ? exp(s) : 0 — all 32 kv bits of q row ln live in one word
        const u32 w = mwv[kt & 1];
        float p[8];
        #pragma unroll
        for (int r = 0; r < 4; ++r) {
            p[r]     = ((w >> (lq4 + r)) & 1u)      ? __expf(sa[r]) : 0.f;
            p[4 + r] = ((w >> (16 + lq4 + r)) & 1u) ? __expf(sb[r]) : 0.f;
        }
        #pragma unroll
        for (int r = 0; r < 8; ++r) lsum += p[r];

        // ring refill for kt+2 — fence pins the load's issue AFTER this iter's DMA
        asm volatile("" ::: "memory");
        {
            const int ktn = (kt + 2 < 32) ? kt + 2 : 31;
            mwv[kt & 1] = broot[ktn];
        }

        // in-register transpose to PV A-layout:
        // target (lq,ln) needs P[q=ln][k=lq*8+j]; k=lq*8+j -> half=lq>>1,
        // src lane = ((lq&1)*2 + (j>>2))*16 + ln, word = (j>>1)&1 of that half.
        u32 w0a = pk2(p[0], p[1]), w1a = pk2(p[2], p[3]);   // half 0 words
        u32 w0b = pk2(p[4], p[5]), w1b = pk2(p[6], p[7]);   // half 1 words
        int r0 = __builtin_amdgcn_ds_bpermute(iA, (int)w0a);
        int r1 = __builtin_amdgcn_ds_bpermute(iA, (int)w1a);
        int r2 = __builtin_amdgcn_ds_bpermute(iB, (int)w0a);
        int r3 = __builtin_amdgcn_ds_bpermute(iB, (int)w1a);
        int r4 = __builtin_amdgcn_ds_bpermute(iA, (int)w0b);
        int r5 = __builtin_amdgcn_ds_bpermute(iA, (int)w1b);
        int r6 = __builtin_amdgcn_ds_bpermute(iB, (int)w0b);
        int r7 = __builtin_amdgcn_ds_bpermute(iB, (int)w1b);
        u32x4 wv;
        wv[0] = lqhi ? (u32)r4 : (u32)r0;
        wv[1] = lqhi ? (u32)r5 : (u32)r1;
        wv[2] = lqhi ? (u32)r6 : (u32)r2;
        wv[3] = lqhi ? (u32)r7 : (u32)r3;
        bf16x8 pa = __builtin_bit_cast(bf16x8, wv);

        // O += P V over all 256 a-cols (no barrier needed — pa is wave-local)
        const char* vbase = Vsb + ln * 64 + vswz;
        #pragma unroll
        for (int t = 0; t < 16; ++t) {
            bf16x8 vf = *(const bf16x8*)(vbase + t * 1024);
            o[t] = mfma16(pa, vf, o[t]);
        }
    }

    // ---- epilogue: all wave-local, no __syncthreads ----
    // row sum: lane (lq,ln) holds q row ln's partial over its 8 kv/iter; reduce lq
    lsum += __shfl_xor(lsum, 16);
    lsum += __shfl_xor(lsum, 32);
    if (lane < 16)
        lp[bs * batch + rs * (qbase + wid * 16 + ln) + ks * kvh] = lsum;

    // accumulate unnormalized partial O into zeroed d_out
    #pragma unroll
    for (int r = 0; r < 4; ++r) {
        float* orow = out + (size_t)(batch * SEQ + qbase + wid * 16 + lq4 + r) * ADIM + ln;
        #pragma unroll
        for (int t = 0; t < 16; ++t)
            atomicAdd(orow + t * 16, o[t][r]);
    }
}

// ---------------- kernel 2b (FALLBACK): R6-proven flash, used if ws too small ----------------
__global__ __launch_bounds__(512, 4) void flash_fb(const float* __restrict__ x,
                                                   const float* __restrict__ WqM,
                                                   const float* __restrict__ bq,
                                                   const char* __restrict__ Ksw,
                                                   const char* __restrict__ Vsw,
                                                   const int* __restrict__ mask,
                                                   const u32* __restrict__ bitw,
                                                   float* __restrict__ lp,
                                                   i64 bs, i64 rs, i64 ks,
                                                   float* __restrict__ out) {
    __shared__ __align__(16) char smem[76288];
    const int tid  = threadIdx.x;
    const int wid  = tid >> 6;
    const int lane = tid & 63;
    const int lq   = lane >> 4;
    const int ln   = lane & 15;
    const int qw   = wid >> 1;
    const int kw   = wid & 1;
    const int batch = blockIdx.x & 7;
    const int kvh   = (blockIdx.x >> 3) & 1;
    const int qbase = (blockIdx.x >> 4) * 64;

    const char* Kb = Ksw + (size_t)batch * 1048576 + (size_t)(kvh * 32) * 16384;
    const char* Vb = Vsw + (size_t)batch * 1048576 + (size_t)(kvh * 32) * 16384;
    char*  Pq_ = smem + 65536 + qw * 1280;
    char*  Pt  = smem + 65536 + wid * 1280;
    float* Ls  = (float*)(smem + 75776);

    const int dhalf = wid >> 2, dqr = wid & 3;
    const char* gsrc0 = (dhalf ? Vb : Kb) + dqr * 4096 + lane * 16;
    const int   ldst0 = dhalf * 16384 + dqr * 4096;

    const int* mroot = mask + (size_t)batch * SEQ * SEQ +
                       (size_t)(qbase + qw * 16) * SEQ + kvh * 1024 + kw * 16 + ln;
    const u32* broot = bitw ? bitw + (size_t)batch * 131072 +
                              (size_t)(qbase + qw * 16) * 64 + kvh * 32
                            : nullptr;
    const int bitpos = kw * 16 + ln;

    {
        char* dl = smem + ldst0;
        #pragma unroll
        for (int i = 0; i < 4; ++i) gld16(gsrc0 + i * 1024, dl + i * 1024);
    }
    asm volatile("" ::: "memory");
    int mv[2][4];
    if (broot) {
        #pragma unroll
        for (int w = 0; w < 2; ++w)
            #pragma unroll
            for (int r = 0; r < 4; ++r)
                mv[w][r] = (int)((broot[(lq * 4 + r) * 64 + w] >> bitpos) & 1u);
    } else {
        #pragma unroll
        for (int w = 0; w < 2; ++w)
            #pragma unroll
            for (int r = 0; r < 4; ++r)
                mv[w][r] = mroot[(size_t)(lq * 4 + r) * SEQ + w * 32];
    }

    bf16x8 qf[8];
    {
        bf16x8 xf[8];
        {
            const float* xp = x + (size_t)(batch * SEQ + qbase + qw * 16 + ln) * EMB;
            #pragma unroll
            for (int c = 0; c < 8; ++c) {
                f32x4 a = *(const f32x4*)(xp + c * 32 + lq * 8);
                f32x4 b = *(const f32x4*)(xp + c * 32 + lq * 8 + 4);
                bf16x8 v;
                v[0] = (bf16_t)a[0]; v[1] = (bf16_t)a[1]; v[2] = (bf16_t)a[2]; v[3] = (bf16_t)a[3];
                v[4] = (bf16_t)b[0]; v[5] = (bf16_t)b[1]; v[6] = (bf16_t)b[2]; v[7] = (bf16_t)b[3];
                xf[c] = v;
            }
        }
        f32x4 qacc[16];
        #pragma unroll
        for (int t = 0; t < 16; ++t) qacc[t] = (f32x4){0.f, 0.f, 0.f, 0.f};

        char* Wsp = smem + 32768;
        const int grp = tid >> 8;
        const int aa  = tid & 255;
        const int e   = ln & 7;
        #pragma unroll 1
        for (int cp = 0; cp < 8; ++cp) {
            __syncthreads();
            const float* wqp = WqM + (size_t)(cp * 32) * 256 + aa;
            #pragma unroll
            for (int i = 0; i < 2; ++i) {
                int ip = grp * 2 + i;
                bf16x8 pk;
                #pragma unroll
                for (int j = 0; j < 8; ++j)
                    pk[j] = (bf16_t)wqp[(size_t)(ip * 8 + j) * 256];
                *(bf16x8*)(Wsp + aa * 128 + ((ip ^ (aa & 7)) * 16)) = pk;
            }
            __syncthreads();
            #pragma unroll
            for (int t = 0; t < 16; ++t) {
                bf16x8 wf = *(const bf16x8*)(Wsp + (t * 16 + ln) * 128 + ((lq ^ e) * 16));
                qacc[t] = mfma16(xf[cp], wf, qacc[t]);
            }
        }
        #pragma unroll
        for (int c = 0; c < 8; ++c) {
            #pragma unroll
            for (int half2 = 0; half2 < 2; ++half2) {
                int t = 2 * c + half2;
                float bb = bq[t * 16 + ln];
                #pragma unroll
                for (int r = 0; r < 4; ++r) {
                    float v = (qacc[t][r] + bb) * 0.0625f;
                    ((bf16_t*)(Pt + (lq * 4 + r) * 80))[half2 * 16 + ln] = (bf16_t)v;
                }
            }
            qf[c] = *(const bf16x8*)(Pt + ln * 80 + lq * 16);
        }
    }

    f32x4 o[8];
    #pragma unroll
    for (int t = 0; t < 8; ++t) o[t] = (f32x4){0.f, 0.f, 0.f, 0.f};
    float lsum[4] = {0.f, 0.f, 0.f, 0.f};

    const int kswz = ln & 7;
    const int vswz = (lq ^ (ln & 3) ^ ((ln >> 2) & 3)) * 16;
    const int n0   = kw * 16 + ln;

    for (int kt = 0; kt < 32; ++kt) {
        asm volatile("s_waitcnt vmcnt(4) lgkmcnt(0)\n\ts_barrier" ::: "memory");
        if (kt + 1 < 32) {
            const char* gs = gsrc0 + (size_t)(kt + 1) * 16384;
            char* dl = smem + ((kt + 1) & 1) * 32768 + ldst0;
            #pragma unroll
            for (int i = 0; i < 4; ++i) gld16(gs + i * 1024, dl + i * 1024);
        }
        const char* Ksb = smem + (kt & 1) * 32768;
        const char* Vsb = Ksb + 16384;

        f32x4 s0 = (f32x4){0.f, 0.f, 0.f, 0.f};
        const char* krow = Ksb + n0 * 512;
        #pragma unroll
        for (int c = 0; c < 8; ++c) {
            bf16x8 kf = *(const bf16x8*)(krow + (((c * 4 + lq) ^ kswz) * 16));
            s0 = mfma16(qf[c], kf, s0);
        }

        const int* mc = mv[kt & 1];
        #pragma unroll
        for (int r = 0; r < 4; ++r) {
            float p0 = mc[r] ? __expf(s0[r]) : 0.f;
            lsum[r] += p0;
            ((bf16_t*)(Pq_ + (lq * 4 + r) * 80))[kw * 16 + ln] = (bf16_t)p0;
        }

        asm volatile("s_waitcnt lgkmcnt(0)\n\ts_barrier" ::: "memory");

        {
            const int ktn = (kt + 2 < 32) ? kt + 2 : 31;
            int* md = mv[kt & 1];
            if (broot) {
                #pragma unroll
                for (int r = 0; r < 4; ++r)
                    md[r] = (int)((broot[(lq * 4 + r) * 64 + ktn] >> bitpos) & 1u);
            } else {
                #pragma unroll
                for (int r = 0; r < 4; ++r)
                    md[r] = mroot[(size_t)(lq * 4 + r) * SEQ + ktn * 32];
            }
        }

        bf16x8 pa0 = *(const bf16x8*)(Pq_ + ln * 80 + lq * 16);

        const char* vbase = Vsb + (kw * 128 + ln) * 64 + vswz;
        #pragma unroll
        for (int t = 0; t < 8; ++t) {
            bf16x8 vf = *(const bf16x8*)(vbase + t * 1024);
            o[t] = mfma16(pa0, vf, o[t]);
        }
    }

    __syncthreads();
    #pragma unroll
    for (int r = 0; r < 4; ++r) {
        float v = lsum[r];
        v += __shfl_xor(v, 1);
        v += __shfl_xor(v, 2);
        v += __shfl_xor(v, 4);
        v += __shfl_xor(v, 8);
        if (ln == 0) Ls[(qw * 2 + kw) * 16 + lq * 4 + r] = v;
        lsum[r] = v;
    }
    __syncthreads();

    if (kw == 0 && ln == 0) {
        #pragma unroll
        for (int r = 0; r < 4; ++r) {
            int row = lq * 4 + r;
            float tot = lsum[r] + Ls[(qw * 2 + 1) * 16 + row];
            lp[bs * batch + rs * (qbase + qw * 16 + row) + ks * kvh] = tot;
        }
    }

    #pragma unroll
    for (int r = 0; r < 4; ++r) {
        float* orow = out + (size_t)(batch * SEQ + qbase + qw * 16 + lq * 4 + r) * ADIM
                      + kw * 128 + ln;
        #pragma unroll
        for (int t = 0; t < 8; ++t)
            atomicAdd(orow + t * 16, o[t][r]);
    }
}

// ---------------- kernel 3: merge/normalize ----------------
// out[row][:] /= (l0[row] + l1[row]) with partial lsums read via (lp, strides).
__global__ __launch_bounds__(256) void merge_kernel(const float* __restrict__ lp,
                                                    i64 bs, i64 rs, i64 ks,
                                                    float* __restrict__ out) {
    int idx  = blockIdx.x * 256 + threadIdx.x;   // x4 elements
    int base = idx * 4;                          // 0 .. 16,777,212
    int row  = base >> 8;                        // global row 0..16383
    int b = row >> 11, r = row & 2047;
    float l0 = lp[bs * b + rs * r];
    float l1 = lp[bs * b + rs * r + ks];
    float inv = 1.0f / (l0 + l1);
    f32x4 v = *(const f32x4*)(out + base);
    v[0] *= inv; v[1] *= inv; v[2] *= inv; v[3] *= inv;
    *(f32x4*)(out + base) = v;
}

// ================= launch =================
extern "C" void kernel_launch(void* const* d_in, const int* in_sizes, int n_in,
                              void* d_out, int out_size, void* d_ws, size_t ws_size,
                              hipStream_t stream) {
    const float* x    = (const float*)d_in[0];
    int*         mask = (int*)d_in[1];
    const float* Wq   = (const float*)d_in[2];
    const float* bq   = (const float*)d_in[3];
    const float* Wk   = (const float*)d_in[4];
    const float* bk   = (const float*)d_in[5];
    const float* Wv   = (const float*)d_in[6];
    const float* bv   = (const float*)d_in[7];
    float* out = (float*)d_out;

    // ws: Ksw [0,8M) | Vsw [8,16M) | bitw [16,20M) | Qsw [20,28M) | lp [28M,+128K)
    char* Ksw = (char*)d_ws;
    char* Vsw = Ksw + (size_t)8 * 1024 * 1024;
    bf16_t* wt = (bf16_t*)d_out;                 // W^T bf16 scratch (3x128KB), pre-memset

    const size_t MB = 1024 * 1024;
    const size_t lsum_bytes = (size_t)2 * BATCH * SEQ * sizeof(float);   // 128 KB
    u32*   bitw = nullptr;
    char*  Qsw  = nullptr;
    float* lp; i64 bs, rs, ks;
    if (ws_size >= 28 * MB + lsum_bytes) {        // full tier: primary flash
        bitw = (u32*)(Ksw + 16 * MB);
        Qsw  = Ksw + 20 * MB;
        lp   = (float*)(Ksw + 28 * MB);
        bs = (i64)2 * SEQ;  rs = 2;  ks = 1;
    } else if (ws_size >= 20 * MB + lsum_bytes) { // R6-proven bitmask tier
        bitw = (u32*)(Ksw + 16 * MB);
        lp   = (float*)(Ksw + 20 * MB);
        bs = (i64)2 * SEQ;  rs = 2;  ks = 1;
    } else if (ws_size >= 16 * MB + lsum_bytes) { // ws-lsum tier
        lp = (float*)(Ksw + 16 * MB);
        bs = (i64)2 * SEQ;  rs = 2;  ks = 1;
    } else {                                      // legacy in-mask parking
        lp = (float*)mask;
        bs = (i64)SEQ * SEQ;  rs = SEQ;  ks = 1024;
    }

    wtkv_kernel<<<768, 256, 0, stream>>>(Wk, Wv, Wq, wt);
    if (bitw) maskbits_kernel<<<4096, 256, 0, stream>>>((const u32*)mask, bitw);
    proj_qkv<<<512, 128, 0, stream>>>(x, wt, bk, bv, bq, Ksw, Vsw, Qsw);
    // zero the f32 accumulator AFTER proj consumed wt (stream-ordered; graph-legal)
    hipMemsetAsync(d_out, 0, (size_t)out_size * sizeof(float), stream);
    if (Qsw)
        flash_kernel<<<512, 256, 0, stream>>>(Qsw, Ksw, Vsw, bitw, lp, bs, rs, ks, out);
    else
        flash_fb<<<512, 512, 0, stream>>>(x, Wq, bq, Ksw, Vsw, mask, bitw,
                                          lp, bs, rs, ks, out);
    merge_kernel<<<4096, 256, 0, stream>>>(lp, bs, rs, ks, out);
}

// Round 9
// 357.895 us; speedup vs baseline: 1.0604x; 1.0054x over previous
//
#include <hip/hip_runtime.h>
#include <hip/hip_bf16.h>
#include <stdint.h>

#define BATCH 8
#define SEQ   2048
#define EMB   256
#define ADIM  256

typedef __bf16 bf16_t;
typedef __attribute__((ext_vector_type(8))) __bf16 bf16x8;
typedef __attribute__((ext_vector_type(4))) float  f32x4;
typedef uint32_t u32;
typedef __attribute__((ext_vector_type(4))) u32 u32x4;
typedef long long i64;

static __device__ __forceinline__ f32x4 mfma16(bf16x8 a, bf16x8 b, f32x4 c) {
    return __builtin_amdgcn_mfma_f32_16x16x32_bf16(a, b, c, 0, 0, 0);
}

// async global->LDS DMA: lds dest = wave-uniform base + lane*16
static __device__ __forceinline__ void gld16(const void* g, void* l) {
    __builtin_amdgcn_global_load_lds((const __attribute__((address_space(1))) u32*)g,
                                     (__attribute__((address_space(3))) u32*)l, 16, 0, 0);
}

// pack two f32 -> one u32 of two bf16 (RNE, same rounding as scalar casts)
static __device__ __forceinline__ u32 pk2(float lo, float hi) {
    u32 a = (u32)__builtin_bit_cast(unsigned short, (bf16_t)lo);
    u32 b = (u32)__builtin_bit_cast(unsigned short, (bf16_t)hi);
    return a | (b << 16);
}

// ---------------- kernel 0: W^T (k,v,q) cast to bf16 -> d_out scratch ----------------
// wt[m][a][e] = (bf16) W_m[e][a], m = 0:K 1:V 2:Q. d_out is dead for flash output
// until the memset; only proj (stream-ordered before it) reads wt.
__global__ __launch_bounds__(256) void wtkv_kernel(const float* __restrict__ Wk,
                                                   const float* __restrict__ Wv,
                                                   const float* __restrict__ Wq,
                                                   bf16_t* __restrict__ wt) {
    int tid = blockIdx.x * 256 + threadIdx.x;   // 0 .. 3*65536-1
    int m = tid >> 16;
    int i = tid & 65535;
    int a = i >> 8, e = i & 255;
    const float* W = (m == 0) ? Wk : (m == 1) ? Wv : Wq;
    wt[m * 65536 + a * 256 + e] = (bf16_t)W[e * 256 + a];
}

// ---------------- kernel 1: fused K+V(+Q) projection + mask bit-packing ----------------
// Byte layouts consumed by flash (K-format also used for Qsw):
//   Ksw: per batch 64 tiles x 16384 B; byte = n*512 + ((cb^(n&7))*16) + j*2
//   Vsw: byte = a*64 + (((k>>3) ^ (a&3) ^ ((a>>2)&3))*16) + (k&7)*2, k = s&31
// Q panel folds bias and 1/sqrt(A)=1/16 (identical math/order to R7).
// R8: the maskbits dispatch is folded in as a grid-stride tail (BW-bound 134 MB
// read overlaps this kernel's MFMA-bound work; one fewer dispatch):
//   bitw word idx = b*131072 + row*64 + w ; bit j set iff mask[b][row][w*32+j] != 0.
__global__ __launch_bounds__(128, 1) void proj_qkv(const float* __restrict__ x,
                                                   const bf16_t* __restrict__ wt,  // in d_out
                                                   const float* __restrict__ bk,
                                                   const float* __restrict__ bv,
                                                   const float* __restrict__ bq,
                                                   const u32* __restrict__ mask_u32,
                                                   char* __restrict__ Ksw,
                                                   char* __restrict__ Vsw,
                                                   char* __restrict__ Qsw,
                                                   u32* __restrict__ bitw) {
    __shared__ __align__(16) char stg[2][10240];   // per-wave repack buffer
    const int tid  = threadIdx.x;
    const int wid  = tid >> 6;
    const int lane = tid & 63;
    const int lq   = lane >> 4;
    const int ln   = lane & 15;
    const int blk  = blockIdx.x;                   // 0..511: one 32-row tile
    const int b    = blk >> 6;                     // batch
    const int tile = blk & 63;                     // tile within batch
    const int mbase = blk * 32 + wid * 16;         // this wave's 16 global rows
    char* S = stg[wid];

    bf16x8 xf[8];
    const float* xp = x + (size_t)(mbase + ln) * EMB;
    #pragma unroll
    for (int c = 0; c < 8; ++c) {
        f32x4 a0 = *(const f32x4*)(xp + c * 32 + lq * 8);
        f32x4 a1 = *(const f32x4*)(xp + c * 32 + lq * 8 + 4);
        bf16x8 v;
        v[0] = (bf16_t)a0[0]; v[1] = (bf16_t)a0[1]; v[2] = (bf16_t)a0[2]; v[3] = (bf16_t)a0[3];
        v[4] = (bf16_t)a1[0]; v[5] = (bf16_t)a1[1]; v[6] = (bf16_t)a1[2]; v[7] = (bf16_t)a1[3];
        xf[c] = v;
    }

    f32x4 acc[16];

    // ======== K projection ========
    #pragma unroll
    for (int t = 0; t < 16; ++t) acc[t] = (f32x4){0.f, 0.f, 0.f, 0.f};
    {
        const bf16_t* w = wt;                      // K panel wt[0][a][e]
        #pragma unroll
        for (int c = 0; c < 8; ++c)
            #pragma unroll
            for (int t = 0; t < 16; ++t) {
                bf16x8 wf = *(const bf16x8*)(w + (size_t)(t * 16 + ln) * 256 + c * 32 + lq * 8);
                acc[t] = mfma16(xf[c], wf, acc[t]);
            }
    }
    #pragma unroll
    for (int t = 0; t < 16; ++t) {
        float bb = bk[t * 16 + ln];
        #pragma unroll
        for (int r = 0; r < 4; ++r)
            *(bf16_t*)(S + (lq * 4 + r) * 512 + (t * 16 + ln) * 2) = (bf16_t)(acc[t][r] + bb);
    }
    asm volatile("s_waitcnt lgkmcnt(0)" ::: "memory");
    {
        char* Kg = Ksw + (size_t)b * 1048576 + (size_t)tile * 16384 + wid * 8192;
        const int rh = lane >> 5;
        const int p  = lane & 31;
        #pragma unroll
        for (int i = 0; i < 8; ++i) {
            int row = i * 2 + rh;
            int n   = wid * 16 + row;
            int cb  = p ^ (n & 7);
            f32x4 ch = *(const f32x4*)(S + row * 512 + cb * 16);
            *(f32x4*)(Kg + row * 512 + p * 16) = ch;
        }
    }

    // ======== Q projection (K-format store; only when Qsw tier engaged) ========
    if (Qsw) {
        #pragma unroll
        for (int t = 0; t < 16; ++t) acc[t] = (f32x4){0.f, 0.f, 0.f, 0.f};
        {
            const bf16_t* w = wt + 131072;         // Q panel wt[2][a][e]
            #pragma unroll
            for (int c = 0; c < 8; ++c)
                #pragma unroll
                for (int t = 0; t < 16; ++t) {
                    bf16x8 wf = *(const bf16x8*)(w + (size_t)(t * 16 + ln) * 256 + c * 32 + lq * 8);
                    acc[t] = mfma16(xf[c], wf, acc[t]);
                }
        }
        #pragma unroll
        for (int t = 0; t < 16; ++t) {
            float bb = bq[t * 16 + ln];
            #pragma unroll
            for (int r = 0; r < 4; ++r)
                *(bf16_t*)(S + (lq * 4 + r) * 512 + (t * 16 + ln) * 2) =
                    (bf16_t)((acc[t][r] + bb) * 0.0625f);
        }
        asm volatile("s_waitcnt lgkmcnt(0)" ::: "memory");
        {
            char* Qg = Qsw + (size_t)b * 1048576 + (size_t)tile * 16384 + wid * 8192;
            const int rh = lane >> 5;
            const int p  = lane & 31;
            #pragma unroll
            for (int i = 0; i < 8; ++i) {
                int row = i * 2 + rh;
                int n   = wid * 16 + row;
                int cb  = p ^ (n & 7);
                f32x4 ch = *(const f32x4*)(S + row * 512 + cb * 16);
                *(f32x4*)(Qg + row * 512 + p * 16) = ch;
            }
        }
    }

    // ======== V projection ========
    #pragma unroll
    for (int t = 0; t < 16; ++t) acc[t] = (f32x4){0.f, 0.f, 0.f, 0.f};
    {
        const bf16_t* w = wt + 65536;              // V panel wt[1][a][e]
        #pragma unroll
        for (int c = 0; c < 8; ++c)
            #pragma unroll
            for (int t = 0; t < 16; ++t) {
                bf16x8 wf = *(const bf16x8*)(w + (size_t)(t * 16 + ln) * 256 + c * 32 + lq * 8);
                acc[t] = mfma16(xf[c], wf, acc[t]);
            }
    }
    #pragma unroll
    for (int t = 0; t < 16; ++t) {
        float bb = bv[t * 16 + ln];
        #pragma unroll
        for (int r = 0; r < 4; ++r)
            *(bf16_t*)(S + (t * 16 + ln) * 40 + (lq * 4 + r) * 2) = (bf16_t)(acc[t][r] + bb);
    }
    asm volatile("s_waitcnt lgkmcnt(0)" ::: "memory");
    {
        char* Vg = Vsw + (size_t)b * 1048576 + (size_t)tile * 16384;
        const int half = lane & 1;
        const int kq   = wid * 2 + half;
        #pragma unroll
        for (int i = 0; i < 8; ++i) {
            int a   = i * 32 + (lane >> 1);
            int pos = kq ^ (a & 3) ^ ((a >> 2) & 3);
            f32x4 ch = *(const f32x4*)(S + a * 40 + half * 16);
            *(f32x4*)(Vg + a * 64 + pos * 16) = ch;
        }
    }

    // ======== fused mask -> bit-words (was maskbits_kernel) ========
    // 1,048,576 words over 65,536 threads = 16 words/thread. Word index advances
    // with tid so a wave reads 64 consecutive 128 B chunks = 8 KB coalesced.
    if (bitw) {
        const int gthreads = 512 * 128;
        const int gt = blockIdx.x * 128 + tid;
        #pragma unroll 1
        for (int wnd = 0; wnd < 16; ++wnd) {
            int idx = wnd * gthreads + gt;
            const u32* src = mask_u32 + (size_t)idx * 32;
            u32 wd = 0;
            #pragma unroll
            for (int q = 0; q < 8; ++q) {
                u32x4 v = *(const u32x4*)(src + q * 4);
                #pragma unroll
                for (int j = 0; j < 4; ++j)
                    wd |= (v[j] ? 1u : 0u) << (q * 4 + j);
            }
            bitw[idx] = wd;
        }
    }
}

// ---------------- kernel 2 (PRIMARY): barrier-light flash, swapped QK ----------------
// R7-proven structure (82 us): 4 waves x 256 threads; wave owns 16 q rows x full
// 32-kv tile x all 256 a-cols. Q from pre-swizzled Qsw. Swapped QK makes P
// lane-local; PV A-fragment built via 4 packs + 8 ds_bpermute + 4 selects — no
// mid barrier, no Pq LDS, no loop ds_write. Sole sync: counted top barrier
// (vmcnt(1) retires this tile's 8 DMA, keeps the young mask word in flight).
// R8 delta: s_setprio(1/0) around the QK and PV MFMA clusters — this structure
// has no mid-barrier lockstep (waves independent between top barriers), the
// regime where setprio measured +4-7% (vs -6% on the old lockstep body).
__global__ __launch_bounds__(256, 2) void flash_kernel(const char* __restrict__ Qsw,
                                                       const char* __restrict__ Ksw,
                                                       const char* __restrict__ Vsw,
                                                       const u32* __restrict__ bitw,
                                                       float* __restrict__ lp,
                                                       i64 bs, i64 rs, i64 ks,
                                                       float* __restrict__ out) {
    // LDS: buf0 [K 16K][V 16K] @0 ; buf1 @32768.
    __shared__ __align__(16) char smem[65536];
    const int tid  = threadIdx.x;
    const int wid  = tid >> 6;    // 0..3: 16-q-row group
    const int lane = tid & 63;
    const int lq   = lane >> 4;
    const int ln   = lane & 15;
    const int batch = blockIdx.x & 7;
    const int kvh   = (blockIdx.x >> 3) & 1;     // kv half of the sequence
    const int qbase = (blockIdx.x >> 4) * 64;

    const char* Kb = Ksw + (size_t)batch * 1048576 + (size_t)(kvh * 32) * 16384;
    const char* Vb = Vsw + (size_t)batch * 1048576 + (size_t)(kvh * 32) * 16384;

    // DMA role: wid 0,1 stage K halves; wid 2,3 stage V halves (8 KB each)
    const char* gsrc0 = ((wid & 2) ? Vb : Kb) + (wid & 1) * 8192 + lane * 16;
    const int   ldst0 = (wid & 2) * 8192 + (wid & 1) * 8192;   // (wid&2)*8192 = 16384 for V

    // ---- issue DMA for tile 0 (oldest vmem ops by construction) ----
    #pragma unroll
    for (int i = 0; i < 8; ++i) gld16(gsrc0 + i * 1024, smem + ldst0 + i * 1024);
    asm volatile("" ::: "memory");

    // mask ring: one word = q row (ln)'s 32 kv bits for tile kt
    const u32* broot = bitw + (size_t)batch * 131072 +
                       (size_t)(qbase + wid * 16 + ln) * 64 + kvh * 32;
    u32 mwv[2];
    mwv[0] = broot[0];
    mwv[1] = broot[1];

    // ---- Q fragments straight from Qsw (K-format; swizzle = row&7) ----
    bf16x8 qf[8];
    {
        const int qr = qbase + wid * 16 + ln;
        const char* qp = Qsw + (size_t)batch * 1048576 +
                         (size_t)(qr >> 5) * 16384 + (size_t)(qr & 31) * 512;
        const int qswz = ln & 7;                  // (qr&31)&7 == ln&7
        #pragma unroll
        for (int c = 0; c < 8; ++c)
            qf[c] = *(const bf16x8*)(qp + (((c * 4 + lq) ^ qswz) * 16));
    }

    f32x4 o[16];
    #pragma unroll
    for (int t = 0; t < 16; ++t) o[t] = (f32x4){0.f, 0.f, 0.f, 0.f};
    float lsum = 0.f;

    const int kswz = ln & 7;
    const int vswz = (lq ^ (ln & 3) ^ ((ln >> 2) & 3)) * 16;
    const int lq4  = lq * 4;
    const int iA   = (((lq & 1) * 2) * 16 + ln) * 4;   // bpermute byte index, lane A
    const int iB   = iA + 64;                          // lane A + 16
    const bool lqhi = (lq & 2) != 0;                   // kv half selector

    for (int kt = 0; kt < 32; ++kt) {
        // counted TOP barrier: retire this tile's 8 DMA (oldest), keep the young
        // mask word in flight; drain own LDS ops (buffer WAR safety for all waves).
        asm volatile("s_waitcnt vmcnt(1) lgkmcnt(0)\n\ts_barrier" ::: "memory");
        if (kt + 1 < 32) {                        // prefetch tile kt+1 (8 KB per wave)
            const char* gs = gsrc0 + (size_t)(kt + 1) * 16384;
            char* dl = smem + ((kt + 1) & 1) * 32768 + ldst0;
            #pragma unroll
            for (int i = 0; i < 8; ++i) gld16(gs + i * 1024, dl + i * 1024);
        }
        const char* Ksb = smem + (kt & 1) * 32768;
        const char* Vsb = Ksb + 16384;

        // S^T = K Q^T : lane (lq,ln) gets S^T[kv = h*16+lq*4+r][q row = ln]
        f32x4 sa = (f32x4){0.f, 0.f, 0.f, 0.f};
        f32x4 sb = (f32x4){0.f, 0.f, 0.f, 0.f};
        const char* krowa = Ksb + ln * 512;
        const char* krowb = Ksb + (16 + ln) * 512;
        __builtin_amdgcn_s_setprio(1);
        #pragma unroll
        for (int c = 0; c < 8; ++c) {
            const int off = ((c * 4 + lq) ^ kswz) * 16;
            bf16x8 ka = *(const bf16x8*)(krowa + off);
            bf16x8 kb = *(const bf16x8*)(krowb + off);
            sa = mfma16(ka, qf[c], sa);
            sb = mfma16(kb, qf[c], sb);
        }
        __builtin_amdgcn_s_setprio(0);

        // p = mask ? exp(s) : 0 — all 32 kv bits of q row ln live in one word
        const u32 w = mwv[kt & 1];
        float p[8];
        #pragma unroll
        for (int r = 0; r < 4; ++r) {
            p[r]     = ((w >> (lq4 + r)) & 1u)      ? __expf(sa[r]) : 0.f;
            p[4 + r] = ((w >> (16 + lq4 + r)) & 1u) ? __expf(sb[r]) : 0.f;
        }
        #pragma unroll
        for (int r = 0; r < 8; ++r) lsum += p[r];

        // ring refill for kt+2 — fence pins the load's issue AFTER this iter's DMA
        asm volatile("" ::: "memory");
        {
            const int ktn = (kt + 2 < 32) ? kt + 2 : 31;
            mwv[kt & 1] = broot[ktn];
        }

        // in-register transpose to PV A-layout:
        // target (lq,ln) needs P[q=ln][k=lq*8+j]; k=lq*8+j -> half=lq>>1,
        // src lane = ((lq&1)*2 + (j>>2))*16 + ln, word = (j>>1)&1 of that half.
        u32 w0a = pk2(p[0], p[1]), w1a = pk2(p[2], p[3]);   // half 0 words
        u32 w0b = pk2(p[4], p[5]), w1b = pk2(p[6], p[7]);   // half 1 words
        int r0 = __builtin_amdgcn_ds_bpermute(iA, (int)w0a);
        int r1 = __builtin_amdgcn_ds_bpermute(iA, (int)w1a);
        int r2 = __builtin_amdgcn_ds_bpermute(iB, (int)w0a);
        int r3 = __builtin_amdgcn_ds_bpermute(iB, (int)w1a);
        int r4 = __builtin_amdgcn_ds_bpermute(iA, (int)w0b);
        int r5 = __builtin_amdgcn_ds_bpermute(iA, (int)w1b);
        int r6 = __builtin_amdgcn_ds_bpermute(iB, (int)w0b);
        int r7 = __builtin_amdgcn_ds_bpermute(iB, (int)w1b);
        u32x4 wv;
        wv[0] = lqhi ? (u32)r4 : (u32)r0;
        wv[1] = lqhi ? (u32)r5 : (u32)r1;
        wv[2] = lqhi ? (u32)r6 : (u32)r2;
        wv[3] = lqhi ? (u32)r7 : (u32)r3;
        bf16x8 pa = __builtin_bit_cast(bf16x8, wv);

        // O += P V over all 256 a-cols (no barrier needed — pa is wave-local)
        const char* vbase = Vsb + ln * 64 + vswz;
        __builtin_amdgcn_s_setprio(1);
        #pragma unroll
        for (int t = 0; t < 16; ++t) {
            bf16x8 vf = *(const bf16x8*)(vbase + t * 1024);
            o[t] = mfma16(pa, vf, o[t]);
        }
        __builtin_amdgcn_s_setprio(0);
    }

    // ---- epilogue: all wave-local, no __syncthreads ----
    // row sum: lane (lq,ln) holds q row ln's partial over its 8 kv/iter; reduce lq
    lsum += __shfl_xor(lsum, 16);
    lsum += __shfl_xor(lsum, 32);
    if (lane < 16)
        lp[bs * batch + rs * (qbase + wid * 16 + ln) + ks * kvh] = lsum;

    // accumulate unnormalized partial O into zeroed d_out
    #pragma unroll
    for (int r = 0; r < 4; ++r) {
        float* orow = out + (size_t)(batch * SEQ + qbase + wid * 16 + lq4 + r) * ADIM + ln;
        #pragma unroll
        for (int t = 0; t < 16; ++t)
            atomicAdd(orow + t * 16, o[t][r]);
    }
}

// ---------------- kernel 2b (FALLBACK): R6-proven flash, used if ws too small ----------------
__global__ __launch_bounds__(512, 4) void flash_fb(const float* __restrict__ x,
                                                   const float* __restrict__ WqM,
                                                   const float* __restrict__ bq,
                                                   const char* __restrict__ Ksw,
                                                   const char* __restrict__ Vsw,
                                                   const int* __restrict__ mask,
                                                   const u32* __restrict__ bitw,
                                                   float* __restrict__ lp,
                                                   i64 bs, i64 rs, i64 ks,
                                                   float* __restrict__ out) {
    __shared__ __align__(16) char smem[76288];
    const int tid  = threadIdx.x;
    const int wid  = tid >> 6;
    const int lane = tid & 63;
    const int lq   = lane >> 4;
    const int ln   = lane & 15;
    const int qw   = wid >> 1;
    const int kw   = wid & 1;
    const int batch = blockIdx.x & 7;
    const int kvh   = (blockIdx.x >> 3) & 1;
    const int qbase = (blockIdx.x >> 4) * 64;

    const char* Kb = Ksw + (size_t)batch * 1048576 + (size_t)(kvh * 32) * 16384;
    const char* Vb = Vsw + (size_t)batch * 1048576 + (size_t)(kvh * 32) * 16384;
    char*  Pq_ = smem + 65536 + qw * 1280;
    char*  Pt  = smem + 65536 + wid * 1280;
    float* Ls  = (float*)(smem + 75776);

    const int dhalf = wid >> 2, dqr = wid & 3;
    const char* gsrc0 = (dhalf ? Vb : Kb) + dqr * 4096 + lane * 16;
    const int   ldst0 = dhalf * 16384 + dqr * 4096;

    const int* mroot = mask + (size_t)batch * SEQ * SEQ +
                       (size_t)(qbase + qw * 16) * SEQ + kvh * 1024 + kw * 16 + ln;
    const u32* broot = bitw ? bitw + (size_t)batch * 131072 +
                              (size_t)(qbase + qw * 16) * 64 + kvh * 32
                            : nullptr;
    const int bitpos = kw * 16 + ln;

    {
        char* dl = smem + ldst0;
        #pragma unroll
        for (int i = 0; i < 4; ++i) gld16(gsrc0 + i * 1024, dl + i * 1024);
    }
    asm volatile("" ::: "memory");
    int mv[2][4];
    if (broot) {
        #pragma unroll
        for (int w = 0; w < 2; ++w)
            #pragma unroll
            for (int r = 0; r < 4; ++r)
                mv[w][r] = (int)((broot[(lq * 4 + r) * 64 + w] >> bitpos) & 1u);
    } else {
        #pragma unroll
        for (int w = 0; w < 2; ++w)
            #pragma unroll
            for (int r = 0; r < 4; ++r)
                mv[w][r] = mroot[(size_t)(lq * 4 + r) * SEQ + w * 32];
    }

    bf16x8 qf[8];
    {
        bf16x8 xf[8];
        {
            const float* xp = x + (size_t)(batch * SEQ + qbase + qw * 16 + ln) * EMB;
            #pragma unroll
            for (int c = 0; c < 8; ++c) {
                f32x4 a = *(const f32x4*)(xp + c * 32 + lq * 8);
                f32x4 b = *(const f32x4*)(xp + c * 32 + lq * 8 + 4);
                bf16x8 v;
                v[0] = (bf16_t)a[0]; v[1] = (bf16_t)a[1]; v[2] = (bf16_t)a[2]; v[3] = (bf16_t)a[3];
                v[4] = (bf16_t)b[0]; v[5] = (bf16_t)b[1]; v[6] = (bf16_t)b[2]; v[7] = (bf16_t)b[3];
                xf[c] = v;
            }
        }
        f32x4 qacc[16];
        #pragma unroll
        for (int t = 0; t < 16; ++t) qacc[t] = (f32x4){0.f, 0.f, 0.f, 0.f};

        char* Wsp = smem + 32768;
        const int grp = tid >> 8;
        const int aa  = tid & 255;
        const int e   = ln & 7;
        #pragma unroll 1
        for (int cp = 0; cp < 8; ++cp) {
            __syncthreads();
            const float* wqp = WqM + (size_t)(cp * 32) * 256 + aa;
            #pragma unroll
            for (int i = 0; i < 2; ++i) {
                int ip = grp * 2 + i;
                bf16x8 pk;
                #pragma unroll
                for (int j = 0; j < 8; ++j)
                    pk[j] = (bf16_t)wqp[(size_t)(ip * 8 + j) * 256];
                *(bf16x8*)(Wsp + aa * 128 + ((ip ^ (aa & 7)) * 16)) = pk;
            }
            __syncthreads();
            #pragma unroll
            for (int t = 0; t < 16; ++t) {
                bf16x8 wf = *(const bf16x8*)(Wsp + (t * 16 + ln) * 128 + ((lq ^ e) * 16));
                qacc[t] = mfma16(xf[cp], wf, qacc[t]);
            }
        }
        #pragma unroll
        for (int c = 0; c < 8; ++c) {
            #pragma unroll
            for (int half2 = 0; half2 < 2; ++half2) {
                int t = 2 * c + half2;
                float bb = bq[t * 16 + ln];
                #pragma unroll
                for (int r = 0; r < 4; ++r) {
                    float v = (qacc[t][r] + bb) * 0.0625f;
                    ((bf16_t*)(Pt + (lq * 4 + r) * 80))[half2 * 16 + ln] = (bf16_t)v;
                }
            }
            qf[c] = *(const bf16x8*)(Pt + ln * 80 + lq * 16);
        }
    }

    f32x4 o[8];
    #pragma unroll
    for (int t = 0; t < 8; ++t) o[t] = (f32x4){0.f, 0.f, 0.f, 0.f};
    float lsum[4] = {0.f, 0.f, 0.f, 0.f};

    const int kswz = ln & 7;
    const int vswz = (lq ^ (ln & 3) ^ ((ln >> 2) & 3)) * 16;
    const int n0   = kw * 16 + ln;

    for (int kt = 0; kt < 32; ++kt) {
        asm volatile("s_waitcnt vmcnt(4) lgkmcnt(0)\n\ts_barrier" ::: "memory");
        if (kt + 1 < 32) {
            const char* gs = gsrc0 + (size_t)(kt + 1) * 16384;
            char* dl = smem + ((kt + 1) & 1) * 32768 + ldst0;
            #pragma unroll
            for (int i = 0; i < 4; ++i) gld16(gs + i * 1024, dl + i * 1024);
        }
        const char* Ksb = smem + (kt & 1) * 32768;
        const char* Vsb = Ksb + 16384;

        f32x4 s0 = (f32x4){0.f, 0.f, 0.f, 0.f};
        const char* krow = Ksb + n0 * 512;
        #pragma unroll
        for (int c = 0; c < 8; ++c) {
            bf16x8 kf = *(const bf16x8*)(krow + (((c * 4 + lq) ^ kswz) * 16));
            s0 = mfma16(qf[c], kf, s0);
        }

        const int* mc = mv[kt & 1];
        #pragma unroll
        for (int r = 0; r < 4; ++r) {
            float p0 = mc[r] ? __expf(s0[r]) : 0.f;
            lsum[r] += p0;
            ((bf16_t*)(Pq_ + (lq * 4 + r) * 80))[kw * 16 + ln] = (bf16_t)p0;
        }

        asm volatile("s_waitcnt lgkmcnt(0)\n\ts_barrier" ::: "memory");

        {
            const int ktn = (kt + 2 < 32) ? kt + 2 : 31;
            int* md = mv[kt & 1];
            if (broot) {
                #pragma unroll
                for (int r = 0; r < 4; ++r)
                    md[r] = (int)((broot[(lq * 4 + r) * 64 + ktn] >> bitpos) & 1u);
            } else {
                #pragma unroll
                for (int r = 0; r < 4; ++r)
                    md[r] = mroot[(size_t)(lq * 4 + r) * SEQ + ktn * 32];
            }
        }

        bf16x8 pa0 = *(const bf16x8*)(Pq_ + ln * 80 + lq * 16);

        const char* vbase = Vsb + (kw * 128 + ln) * 64 + vswz;
        #pragma unroll
        for (int t = 0; t < 8; ++t) {
            bf16x8 vf = *(const bf16x8*)(vbase + t * 1024);
            o[t] = mfma16(pa0, vf, o[t]);
        }
    }

    __syncthreads();
    #pragma unroll
    for (int r = 0; r < 4; ++r) {
        float v = lsum[r];
        v += __shfl_xor(v, 1);
        v += __shfl_xor(v, 2);
        v += __shfl_xor(v, 4);
        v += __shfl_xor(v, 8);
        if (ln == 0) Ls[(qw * 2 + kw) * 16 + lq * 4 + r] = v;
        lsum[r] = v;
    }
    __syncthreads();

    if (kw == 0 && ln == 0) {
        #pragma unroll
        for (int r = 0; r < 4; ++r) {
            int row = lq * 4 + r;
            float tot = lsum[r] + Ls[(qw * 2 + 1) * 16 + row];
            lp[bs * batch + rs * (qbase + qw * 16 + row) + ks * kvh] = tot;
        }
    }

    #pragma unroll
    for (int r = 0; r < 4; ++r) {
        float* orow = out + (size_t)(batch * SEQ + qbase + qw * 16 + lq * 4 + r) * ADIM
                      + kw * 128 + ln;
        #pragma unroll
        for (int t = 0; t < 8; ++t)
            atomicAdd(orow + t * 16, o[t][r]);
    }
}

// ---------------- kernel 3: merge/normalize ----------------
// out[row][:] /= (l0[row] + l1[row]) with partial lsums read via (lp, strides).
__global__ __launch_bounds__(256) void merge_kernel(const float* __restrict__ lp,
                                                    i64 bs, i64 rs, i64 ks,
                                                    float* __restrict__ out) {
    int idx  = blockIdx.x * 256 + threadIdx.x;   // x4 elements
    int base = idx * 4;                          // 0 .. 16,777,212
    int row  = base >> 8;                        // global row 0..16383
    int b = row >> 11, r = row & 2047;
    float l0 = lp[bs * b + rs * r];
    float l1 = lp[bs * b + rs * r + ks];
    float inv = 1.0f / (l0 + l1);
    f32x4 v = *(const f32x4*)(out + base);
    v[0] *= inv; v[1] *= inv; v[2] *= inv; v[3] *= inv;
    *(f32x4*)(out + base) = v;
}

// ================= launch =================
extern "C" void kernel_launch(void* const* d_in, const int* in_sizes, int n_in,
                              void* d_out, int out_size, void* d_ws, size_t ws_size,
                              hipStream_t stream) {
    const float* x    = (const float*)d_in[0];
    int*         mask = (int*)d_in[1];
    const float* Wq   = (const float*)d_in[2];
    const float* bq   = (const float*)d_in[3];
    const float* Wk   = (const float*)d_in[4];
    const float* bk   = (const float*)d_in[5];
    const float* Wv   = (const float*)d_in[6];
    const float* bv   = (const float*)d_in[7];
    float* out = (float*)d_out;

    // ws: Ksw [0,8M) | Vsw [8,16M) | bitw [16,20M) | Qsw [20,28M) | lp [28M,+128K)
    char* Ksw = (char*)d_ws;
    char* Vsw = Ksw + (size_t)8 * 1024 * 1024;
    bf16_t* wt = (bf16_t*)d_out;                 // W^T bf16 scratch (3x128KB), pre-memset

    const size_t MB = 1024 * 1024;
    const size_t lsum_bytes = (size_t)2 * BATCH * SEQ * sizeof(float);   // 128 KB
    u32*   bitw = nullptr;
    char*  Qsw  = nullptr;
    float* lp; i64 bs, rs, ks;
    if (ws_size >= 28 * MB + lsum_bytes) {        // full tier: primary flash
        bitw = (u32*)(Ksw + 16 * MB);
        Qsw  = Ksw + 20 * MB;
        lp   = (float*)(Ksw + 28 * MB);
        bs = (i64)2 * SEQ;  rs = 2;  ks = 1;
    } else if (ws_size >= 20 * MB + lsum_bytes) { // bitmask tier (fallback flash)
        bitw = (u32*)(Ksw + 16 * MB);
        lp   = (float*)(Ksw + 20 * MB);
        bs = (i64)2 * SEQ;  rs = 2;  ks = 1;
    } else if (ws_size >= 16 * MB + lsum_bytes) { // ws-lsum tier
        lp = (float*)(Ksw + 16 * MB);
        bs = (i64)2 * SEQ;  rs = 2;  ks = 1;
    } else {                                      // legacy in-mask parking
        lp = (float*)mask;
        bs = (i64)SEQ * SEQ;  rs = SEQ;  ks = 1024;
    }

    wtkv_kernel<<<768, 256, 0, stream>>>(Wk, Wv, Wq, wt);
    proj_qkv<<<512, 128, 0, stream>>>(x, wt, bk, bv, bq, (const u32*)mask,
                                      Ksw, Vsw, Qsw, bitw);
    // zero the f32 accumulator AFTER proj consumed wt (stream-ordered; graph-legal)
    hipMemsetAsync(d_out, 0, (size_t)out_size * sizeof(float), stream);
    if (Qsw)
        flash_kernel<<<512, 256, 0, stream>>>(Qsw, Ksw, Vsw, bitw, lp, bs, rs, ks, out);
    else
        flash_fb<<<512, 512, 0, stream>>>(x, Wq, bq, Ksw, Vsw, mask, bitw,
                                          lp, bs, rs, ks, out);
    merge_kernel<<<4096, 256, 0, stream>>>(lp, bs, rs, ks, out);
}